// Round 2
// baseline (250.698 us; speedup 1.0000x reference)
//
#include <hip/hip_runtime.h>
#include <hip/hip_bf16.h>

// out[n] = sum_m exp(-GAMMA * max(||x_n||^2 + ||y_m||^2 - 2 x.y, 0)) * W[m] + b
// n=16384, m=8192, d=512.
// Round 2: 256x256 8-phase deep-pipelined bf16 MFMA GEMM (m201-style template):
//   8 waves (2Mx4N), BK=64, 128 KiB LDS double-buffer, counted vmcnt(4),
//   XOR-granule swizzle (conflict-free ds_read_b128, staged via pre-swizzled
//   global source), XCD-bijective block swizzle, fused exp+rowsum epilogue.
//
// Workspace: Xb bf16[16384*512] @0, Yb bf16[8192*512] @16777216,
//            x2 f32[16384] @25165824, y2 f32[8192] @25231360.

#define GAMMA 0.002f

typedef __bf16 bf16x8 __attribute__((ext_vector_type(8)));
typedef float  f32x4  __attribute__((ext_vector_type(4)));
typedef __attribute__((address_space(3))) void lds_void_t;
typedef __attribute__((address_space(1))) const void gl_void_t;

// ---------------- prep: f32 -> bf16 + row squared-norm (one wave per row, d=512)
__global__ __launch_bounds__(256) void prep_kernel(const float* __restrict__ src,
                                                   __bf16* __restrict__ dst,
                                                   float* __restrict__ norms,
                                                   int nrows) {
    const int wid  = threadIdx.x >> 6;
    const int lane = threadIdx.x & 63;
    const int row  = blockIdx.x * 4 + wid;
    if (row >= nrows) return;
    const float4* s = reinterpret_cast<const float4*>(src + (size_t)row * 512);
    float4 v0 = s[lane * 2];
    float4 v1 = s[lane * 2 + 1];
    float acc = v0.x * v0.x + v0.y * v0.y + v0.z * v0.z + v0.w * v0.w
              + v1.x * v1.x + v1.y * v1.y + v1.z * v1.z + v1.w * v1.w;
    bf16x8 o;
    o[0] = (__bf16)v0.x; o[1] = (__bf16)v0.y; o[2] = (__bf16)v0.z; o[3] = (__bf16)v0.w;
    o[4] = (__bf16)v1.x; o[5] = (__bf16)v1.y; o[6] = (__bf16)v1.z; o[7] = (__bf16)v1.w;
    *reinterpret_cast<bf16x8*>(dst + (size_t)row * 512 + lane * 8) = o;
#pragma unroll
    for (int off = 32; off >= 1; off >>= 1) acc += __shfl_xor(acc, off, 64);
    if (lane == 0) norms[row] = acc;
}

__global__ void init_out(float* __restrict__ out, const float* __restrict__ b, int n) {
    int i = blockIdx.x * blockDim.x + threadIdx.x;
    if (i < n) out[i] = b[0];
}

// ---------------- LDS geometry ----------------
// A: [dbuf d][half h][row r 0..127][k 0..63] bf16 at byte (d*2+h)*16384 + r*128 + col
// B: same at +65536.  Granule swizzle: 16B granule g (=k/8) stored at column
// g' = g ^ (r&7).  Staged linearly via global_load_lds with the inverse
// permutation applied to the per-lane GLOBAL source address (rule #21).

// ds_read macros: aBase/bBase are per-lane byte bases; d, rb/cb, ks are literals.
#define DSR_A(d, rb, ks) (*reinterpret_cast<const bf16x8*>( \
    &smem[(aBase + (d)*32768 + (rb)*2048) ^ ((ks)*64)]))
#define DSR_B(d, cb, ks) (*reinterpret_cast<const bf16x8*>( \
    &smem[(bBase + (d)*32768 + (cb)*2048) ^ ((ks)*64)]))

// Stage one half-tile (128 rows x 64 k): this wave's 16 rows via 2 x 1KB loads.
// GW = matrix base + (tileRowBase + wid*16)*512 + per-lane swizzled offset.
#define STAGE(GW, MOFF, D, H, KT) do { \
    __builtin_amdgcn_global_load_lds((gl_void_t*)((GW) + (size_t)((H)*128)*512 + (KT)*64), \
        (lds_void_t*)(smem + (MOFF) + ((D)*2+(H))*16384 + swave), 16, 0, 0); \
    __builtin_amdgcn_global_load_lds((gl_void_t*)((GW) + (size_t)((H)*128 + 8)*512 + (KT)*64), \
        (lds_void_t*)(smem + (MOFF) + ((D)*2+(H))*16384 + swave + 1024), 16, 0, 0); \
} while (0)

#define VM4 asm volatile("s_waitcnt vmcnt(4)" ::: "memory")
#define VM0 asm volatile("s_waitcnt vmcnt(0)" ::: "memory")
#define VMNONE ((void)0)

// One phase: ds-reads || stage 1 half-tile -> [vmcnt] -> barrier -> 16 MFMA -> barrier
#define PHASE(d, q, READB, STAGE_STMT, VMSTMT) do { \
    bf16x8 a00 = DSR_A(d, 2*(q),   0); \
    bf16x8 a01 = DSR_A(d, 2*(q),   1); \
    bf16x8 a10 = DSR_A(d, 2*(q)+1, 0); \
    bf16x8 a11 = DSR_A(d, 2*(q)+1, 1); \
    if (READB) { \
        _Pragma("unroll") \
        for (int cb = 0; cb < 4; ++cb) { \
            bfr[cb][0] = DSR_B(d, cb, 0); \
            bfr[cb][1] = DSR_B(d, cb, 1); \
        } \
    } \
    STAGE_STMT; \
    VMSTMT; \
    asm volatile("s_barrier" ::: "memory"); \
    __builtin_amdgcn_s_setprio(1); \
    _Pragma("unroll") \
    for (int cb = 0; cb < 4; ++cb) { \
        acc[2*(q)][cb]   = __builtin_amdgcn_mfma_f32_16x16x32_bf16(a00, bfr[cb][0], acc[2*(q)][cb],   0, 0, 0); \
        acc[2*(q)][cb]   = __builtin_amdgcn_mfma_f32_16x16x32_bf16(a01, bfr[cb][1], acc[2*(q)][cb],   0, 0, 0); \
        acc[2*(q)+1][cb] = __builtin_amdgcn_mfma_f32_16x16x32_bf16(a10, bfr[cb][0], acc[2*(q)+1][cb], 0, 0, 0); \
        acc[2*(q)+1][cb] = __builtin_amdgcn_mfma_f32_16x16x32_bf16(a11, bfr[cb][1], acc[2*(q)+1][cb], 0, 0, 0); \
    } \
    __builtin_amdgcn_s_setprio(0); \
    asm volatile("s_barrier" ::: "memory"); \
} while (0)

// grid: 64 tile_n x 32 tile_m = 2048 blocks, 512 threads (8 waves, 2x4).
__global__ __launch_bounds__(512, 2) void rbf_gemm(
    const __bf16* __restrict__ Xb, const __bf16* __restrict__ Yb,
    const float* __restrict__ x2, const float* __restrict__ y2,
    const float* __restrict__ W, float* __restrict__ out) {
    __shared__ __align__(128) char smem[131072];

    const int tid  = threadIdx.x;
    const int wid  = tid >> 6;
    const int lane = tid & 63;
    const int wr   = wid >> 2;      // 0..1 (row half)
    const int wc   = wid & 3;       // 0..3 (col quarter)

    // XCD-bijective swizzle: xcd gets 8 consecutive tile_n rows, sweeps tile_m.
    const int xcd    = blockIdx.x & 7;
    const int idx    = blockIdx.x >> 3;          // 0..255
    const int tile_m = idx >> 3;                 // 0..31
    const int tile_n = xcd * 8 + (idx & 7);      // 0..63
    const int tnBase = tile_n * 256;
    const int tmBase = tile_m * 256;

    // ds_read per-lane bases (byte offsets into smem)
    const int rl   = lane & 15;
    const int cb0  = (((lane >> 4) ^ (lane & 7)) & 7) * 16;       // swizzled col, ks=0
    const int aBase = wr * 16384 + rl * 128 + cb0;
    const int bBase = 65536 + (wc >> 1) * 16384 + ((wc & 1) * 64 + rl) * 128 + cb0;

    // staging: per-lane pre-swizzled global offset (elems) + wave LDS window
    const int gOff  = (lane >> 3) * 512 + (((lane & 7) ^ (lane >> 3)) * 8);
    const int swave = wid * 2048;
    const __bf16* sA = Xb + (size_t)(tnBase + wid * 16) * 512 + gOff;
    const __bf16* sB = Yb + (size_t)(tmBase + wid * 16) * 512 + gOff;

    f32x4  acc[8][4] = {};
    bf16x8 bfr[4][2];

    // ---- prologue: tile0 A+B into dbuf0, tile1 B into dbuf1 (A1[t1] staged in ph1-2)
    STAGE(sA, 0,     0, 0, 0);
    STAGE(sA, 0,     0, 1, 0);
    STAGE(sB, 65536, 0, 0, 0);
    STAGE(sB, 65536, 0, 1, 0);
    STAGE(sB, 65536, 1, 0, 1);
    STAGE(sB, 65536, 1, 1, 1);
    VM4;                      // tile0 A+B resident; tile1 B (4 loads) in flight
    asm volatile("s_barrier" ::: "memory");

    // ---- steady state: iter i computes K-tiles 2i (dbuf0), 2i+1 (dbuf1)
    for (int i = 0; i < 3; ++i) {
        const int kt1 = 2 * i + 1, kt2 = 2 * i + 2, kt3 = 2 * i + 3;
        PHASE(0, 0, true,  STAGE(sA, 0,     1, 0, kt1), VMNONE);
        PHASE(0, 1, false, STAGE(sA, 0,     1, 1, kt1), VMNONE);
        PHASE(0, 2, false, STAGE(sB, 65536, 0, 0, kt2), VMNONE);
        PHASE(0, 3, false, STAGE(sB, 65536, 0, 1, kt2), VM4);
        PHASE(1, 0, true,  STAGE(sA, 0,     0, 0, kt2), VMNONE);
        PHASE(1, 1, false, STAGE(sA, 0,     0, 1, kt2), VMNONE);
        PHASE(1, 2, false, STAGE(sB, 65536, 1, 0, kt3), VMNONE);
        PHASE(1, 3, false, STAGE(sB, 65536, 1, 1, kt3), VM4);
    }
    // ---- tail: K-tiles 6 (dbuf0), 7 (dbuf1); only A1[t7] still to stage
    PHASE(0, 0, true,  STAGE(sA, 0, 1, 0, 7), VMNONE);
    PHASE(0, 1, false, STAGE(sA, 0, 1, 1, 7), VMNONE);
    PHASE(0, 2, false, VMNONE,                VMNONE);
    PHASE(0, 3, false, VMNONE,                VM0);
    PHASE(1, 0, true,  VMNONE,                VMNONE);
    PHASE(1, 1, false, VMNONE,                VMNONE);
    PHASE(1, 2, false, VMNONE,                VMNONE);
    PHASE(1, 3, false, VMNONE,                VMNONE);

    // ---- epilogue: exp + weighted row-sum, 16-lane reduce, atomic into out
    // C/D layout (16x16x32): col = lane&15 (m), row = (lane>>4)*4 + reg (n)
    const int lcol = lane & 15, lrow = lane >> 4;
    float y2v[4], wv[4];
#pragma unroll
    for (int cb = 0; cb < 4; ++cb) {
        int m = tmBase + wc * 64 + cb * 16 + lcol;
        y2v[cb] = y2[m];
        wv[cb]  = W[m];
    }
#pragma unroll
    for (int rb = 0; rb < 8; ++rb) {
#pragma unroll
        for (int i2 = 0; i2 < 4; ++i2) {
            const int n = tnBase + wr * 128 + rb * 16 + lrow * 4 + i2;
            const float x2n = x2[n];
            float s = 0.f;
#pragma unroll
            for (int cb = 0; cb < 4; ++cb) {
                float d2 = x2n + y2v[cb] - 2.0f * acc[rb][cb][i2];
                d2 = fmaxf(d2, 0.f);
                s += __expf(-GAMMA * d2) * wv[cb];
            }
#pragma unroll
            for (int off = 1; off < 16; off <<= 1) s += __shfl_xor(s, off, 64);
            if (lcol == 0) atomicAdd(&out[n], s);
        }
    }
}

extern "C" void kernel_launch(void* const* d_in, const int* in_sizes, int n_in,
                              void* d_out, int out_size, void* d_ws, size_t ws_size,
                              hipStream_t stream) {
    const float* X = (const float*)d_in[0];   // 16384 x 512
    const float* Y = (const float*)d_in[1];   //  8192 x 512
    const float* W = (const float*)d_in[2];   // 8192
    const float* b = (const float*)d_in[3];   // 1
    float* out = (float*)d_out;               // 16384

    char* ws = (char*)d_ws;
    __bf16* Xb = (__bf16*)(ws);
    __bf16* Yb = (__bf16*)(ws + 16777216);
    float*  x2 = (float*)(ws + 16777216 + 8388608);
    float*  y2 = (float*)(ws + 16777216 + 8388608 + 65536);

    prep_kernel<<<4096, 256, 0, stream>>>(X, Xb, x2, 16384);
    prep_kernel<<<2048, 256, 0, stream>>>(Y, Yb, y2, 8192);
    init_out<<<64, 256, 0, stream>>>(out, b, 16384);
    rbf_gemm<<<2048, 512, 0, stream>>>(Xb, Yb, x2, y2, W, out);
}